// Round 1
// baseline (1112.464 us; speedup 1.0000x reference)
//
#include <hip/hip_runtime.h>
#include <hip/hip_bf16.h>

#define E_     8
#define C_     1024
#define H_     4096
#define N_TOK  4096
#define TOPK   2
#define NSLOT  (N_TOK*TOPK)   // 8192
#define SPAD   (NSLOT+128)    // padded rows for tile-tail reads

#define BM 128
#define BN 128
#define BK 32
#define LPAD 40               // LDS row stride (elements): 80B, 16B-aligned, 2-way-bank-safe

typedef __attribute__((ext_vector_type(4))) float f32x4;
typedef __attribute__((ext_vector_type(8))) short short8;

__device__ __forceinline__ unsigned short f2bf(float f) {
    return __builtin_bit_cast(unsigned short, __float2bfloat16(f));
}

// ---------------- router: 1 wave per token ----------------
__global__ void router_kernel(const float* __restrict__ x, const float* __restrict__ Wg,
                              int* __restrict__ sel, float* __restrict__ wts,
                              int* __restrict__ counts) {
    int wave = (blockIdx.x * blockDim.x + threadIdx.x) >> 6;
    int lane = threadIdx.x & 63;
    if (wave >= N_TOK) return;
    const float* xr = x + (size_t)wave * C_;
    float acc[E_];
#pragma unroll
    for (int e = 0; e < E_; ++e) acc[e] = 0.f;
    for (int c = lane; c < C_; c += 64) {
        float xv = xr[c];
#pragma unroll
        for (int e = 0; e < E_; ++e) acc[e] += xv * Wg[e * C_ + c];
    }
#pragma unroll
    for (int e = 0; e < E_; ++e) {
#pragma unroll
        for (int off = 32; off > 0; off >>= 1) acc[e] += __shfl_xor(acc[e], off);
    }
    if (lane == 0) {
        float mx = acc[0];
#pragma unroll
        for (int e = 1; e < E_; ++e) mx = fmaxf(mx, acc[e]);
        float p[E_]; float s = 0.f;
#pragma unroll
        for (int e = 0; e < E_; ++e) { p[e] = __expf(acc[e] - mx); s += p[e]; }
        float inv = 1.f / s;
#pragma unroll
        for (int e = 0; e < E_; ++e) p[e] *= inv;
        int b0 = 0; float v0 = p[0];
#pragma unroll
        for (int e = 1; e < E_; ++e) if (p[e] > v0) { v0 = p[e]; b0 = e; }
        int b1 = -1; float v1 = -1.f;
#pragma unroll
        for (int e = 0; e < E_; ++e) { if (e != b0 && p[e] > v1) { v1 = p[e]; b1 = e; } }
        float isum = 1.f / (v0 + v1);
        sel[wave*2]   = b0; sel[wave*2+1] = b1;
        wts[wave*2]   = v0 * isum; wts[wave*2+1] = v1 * isum;
        atomicAdd(&counts[b0], 1);
        atomicAdd(&counts[b1], 1);
    }
}

// ---------------- scan: exclusive prefix over 8 counts ----------------
__global__ void scan_kernel(const int* __restrict__ counts, int* __restrict__ offsets) {
    if (threadIdx.x == 0) {
        int s = 0;
        for (int e = 0; e < E_; ++e) { offsets[e] = s; s += counts[e]; }
    }
}

// ---------------- scatter+gather: 1 wave per (token, k) slot ----------------
__global__ void scatter_kernel(const float* __restrict__ x, const int* __restrict__ sel,
                               const float* __restrict__ wts, const int* __restrict__ offsets,
                               int* __restrict__ cursors, int* __restrict__ token_of,
                               float* __restrict__ slotw, unsigned short* __restrict__ Xg) {
    int slot_id = (blockIdx.x * blockDim.x + threadIdx.x) >> 6;
    int lane = threadIdx.x & 63;
    if (slot_id >= NSLOT) return;
    int n = slot_id >> 1, k = slot_id & 1;
    int pos = 0;
    if (lane == 0) {
        int e = sel[n*2 + k];
        pos = offsets[e] + atomicAdd(&cursors[e], 1);
        token_of[pos] = n;
        slotw[pos] = wts[n*2 + k];
    }
    pos = __shfl(pos, 0);
    const float* xr = x + (size_t)n * C_;
    unsigned short* dst = Xg + (size_t)pos * C_;
    for (int c0 = lane * 4; c0 < C_; c0 += 256) {
        float4 v = *(const float4*)(xr + c0);
        ushort4 b;
        b.x = f2bf(v.x); b.y = f2bf(v.y); b.z = f2bf(v.z); b.w = f2bf(v.w);
        *(ushort4*)(dst + c0) = b;
    }
}

// ---------------- GEMM1: G = silu(Xg*W1) .* (Xg*W3), per-expert segments ----------------
__global__ __launch_bounds__(256, 2) void gemm1_kernel(
        const unsigned short* __restrict__ Xg, const float* __restrict__ W1,
        const float* __restrict__ W3, unsigned short* __restrict__ G,
        const int* __restrict__ counts, const int* __restrict__ offsets) {
    int ct = blockIdx.x;            // col tile over H: 0..31
    int rslot = blockIdx.y;         // e*32 + rt
    int e = rslot >> 5, rt = rslot & 31;
    int ne = counts[e];
    if (rt * BM >= ne) return;
    int row0 = offsets[e] + rt * BM;
    int n0 = ct * BN;

    __shared__ unsigned short As[BM][LPAD];
    __shared__ unsigned short B1s[BN][LPAD];   // transposed: [n][k]
    __shared__ unsigned short B3s[BN][LPAD];

    int tid = threadIdx.x;
    int lane = tid & 63, wid = tid >> 6;
    int wr = (wid >> 1) * 64, wc = (wid & 1) * 64;

    f32x4 acc1[4][4], acc3[4][4];
#pragma unroll
    for (int m = 0; m < 4; ++m)
#pragma unroll
        for (int n = 0; n < 4; ++n) {
            acc1[m][n] = (f32x4){0.f,0.f,0.f,0.f};
            acc3[m][n] = (f32x4){0.f,0.f,0.f,0.f};
        }

    const float* B1p = W1 + (size_t)e * C_ * H_ + n0;
    const float* B3p = W3 + (size_t)e * C_ * H_ + n0;

    int chunk = tid & 3, rr = tid >> 2;       // A staging: 16B chunk, row
    int kq = tid >> 5, n4 = tid & 31;         // B staging: 4 k-rows x 4 cols

    for (int k0 = 0; k0 < C_; k0 += BK) {
        __syncthreads();
        // stage A (bf16 copy)
#pragma unroll
        for (int h = 0; h < 2; ++h) {
            int row = rr + h * 64;
            uint4 v = *(const uint4*)(Xg + (size_t)(row0 + row) * C_ + k0 + chunk * 8);
            *(uint4*)&As[row][chunk * 8] = v;
        }
        // stage B1/B3: load fp32 rows coalesced, convert, write transposed
        {
            float4 r0 = *(const float4*)(B1p + (size_t)(k0 + kq*4 + 0) * H_ + n4*4);
            float4 r1 = *(const float4*)(B1p + (size_t)(k0 + kq*4 + 1) * H_ + n4*4);
            float4 r2 = *(const float4*)(B1p + (size_t)(k0 + kq*4 + 2) * H_ + n4*4);
            float4 r3 = *(const float4*)(B1p + (size_t)(k0 + kq*4 + 3) * H_ + n4*4);
            ushort4 w0 = {f2bf(r0.x), f2bf(r1.x), f2bf(r2.x), f2bf(r3.x)};
            ushort4 w1 = {f2bf(r0.y), f2bf(r1.y), f2bf(r2.y), f2bf(r3.y)};
            ushort4 w2 = {f2bf(r0.z), f2bf(r1.z), f2bf(r2.z), f2bf(r3.z)};
            ushort4 w3 = {f2bf(r0.w), f2bf(r1.w), f2bf(r2.w), f2bf(r3.w)};
            *(ushort4*)&B1s[n4*4+0][kq*4] = w0;
            *(ushort4*)&B1s[n4*4+1][kq*4] = w1;
            *(ushort4*)&B1s[n4*4+2][kq*4] = w2;
            *(ushort4*)&B1s[n4*4+3][kq*4] = w3;
            r0 = *(const float4*)(B3p + (size_t)(k0 + kq*4 + 0) * H_ + n4*4);
            r1 = *(const float4*)(B3p + (size_t)(k0 + kq*4 + 1) * H_ + n4*4);
            r2 = *(const float4*)(B3p + (size_t)(k0 + kq*4 + 2) * H_ + n4*4);
            r3 = *(const float4*)(B3p + (size_t)(k0 + kq*4 + 3) * H_ + n4*4);
            w0 = (ushort4){f2bf(r0.x), f2bf(r1.x), f2bf(r2.x), f2bf(r3.x)};
            w1 = (ushort4){f2bf(r0.y), f2bf(r1.y), f2bf(r2.y), f2bf(r3.y)};
            w2 = (ushort4){f2bf(r0.z), f2bf(r1.z), f2bf(r2.z), f2bf(r3.z)};
            w3 = (ushort4){f2bf(r0.w), f2bf(r1.w), f2bf(r2.w), f2bf(r3.w)};
            *(ushort4*)&B3s[n4*4+0][kq*4] = w0;
            *(ushort4*)&B3s[n4*4+1][kq*4] = w1;
            *(ushort4*)&B3s[n4*4+2][kq*4] = w2;
            *(ushort4*)&B3s[n4*4+3][kq*4] = w3;
        }
        __syncthreads();
        // fragments + MFMA
        int q = lane >> 4, fr = lane & 15;
        short8 a[4], b1[4], b3[4];
#pragma unroll
        for (int m = 0; m < 4; ++m) a[m] = *(const short8*)&As[wr + m*16 + fr][q*8];
#pragma unroll
        for (int n = 0; n < 4; ++n) {
            b1[n] = *(const short8*)&B1s[wc + n*16 + fr][q*8];
            b3[n] = *(const short8*)&B3s[wc + n*16 + fr][q*8];
        }
#pragma unroll
        for (int m = 0; m < 4; ++m)
#pragma unroll
            for (int n = 0; n < 4; ++n) {
                acc1[m][n] = __builtin_amdgcn_mfma_f32_16x16x32_bf16(a[m], b1[n], acc1[m][n], 0, 0, 0);
                acc3[m][n] = __builtin_amdgcn_mfma_f32_16x16x32_bf16(a[m], b3[n], acc3[m][n], 0, 0, 0);
            }
    }
    // epilogue: silu(h1)*h3 -> bf16 G  (C/D: col=lane&15, row=(lane>>4)*4+reg)
    int q = lane >> 4, cfr = lane & 15;
#pragma unroll
    for (int m = 0; m < 4; ++m) {
#pragma unroll
        for (int rg = 0; rg < 4; ++rg) {
            int row = wr + m*16 + q*4 + rg;
            if (rt * BM + row < ne) {
                size_t gbase = (size_t)(row0 + row) * H_ + n0;
#pragma unroll
                for (int n = 0; n < 4; ++n) {
                    float h1 = acc1[m][n][rg];
                    float h3 = acc3[m][n][rg];
                    float g = h1 * h3 / (1.f + __expf(-h1));
                    G[gbase + wc + n*16 + cfr] = f2bf(g);
                }
            }
        }
    }
}

// ---------------- GEMM2: out[token] += w * (G * W2), per-expert segments ----------------
__global__ __launch_bounds__(256, 2) void gemm2_kernel(
        const unsigned short* __restrict__ G, const float* __restrict__ W2,
        float* __restrict__ out, const int* __restrict__ counts,
        const int* __restrict__ offsets, const int* __restrict__ token_of,
        const float* __restrict__ slotw) {
    int ct = blockIdx.x;            // col tile over C: 0..7
    int rslot = blockIdx.y;
    int e = rslot >> 5, rt = rslot & 31;
    int ne = counts[e];
    if (rt * BM >= ne) return;
    int row0 = offsets[e] + rt * BM;
    int n0 = ct * BN;

    __shared__ unsigned short As[BM][LPAD];
    __shared__ unsigned short Bs[BN][LPAD];

    int tid = threadIdx.x;
    int lane = tid & 63, wid = tid >> 6;
    int wr = (wid >> 1) * 64, wc = (wid & 1) * 64;

    f32x4 acc[4][4];
#pragma unroll
    for (int m = 0; m < 4; ++m)
#pragma unroll
        for (int n = 0; n < 4; ++n) acc[m][n] = (f32x4){0.f,0.f,0.f,0.f};

    const float* Bp = W2 + (size_t)e * H_ * C_ + n0;
    int chunk = tid & 3, rr = tid >> 2;
    int kq = tid >> 5, n4 = tid & 31;

    for (int k0 = 0; k0 < H_; k0 += BK) {
        __syncthreads();
#pragma unroll
        for (int h = 0; h < 2; ++h) {
            int row = rr + h * 64;
            uint4 v = *(const uint4*)(G + (size_t)(row0 + row) * H_ + k0 + chunk * 8);
            *(uint4*)&As[row][chunk * 8] = v;
        }
        {
            float4 r0 = *(const float4*)(Bp + (size_t)(k0 + kq*4 + 0) * C_ + n4*4);
            float4 r1 = *(const float4*)(Bp + (size_t)(k0 + kq*4 + 1) * C_ + n4*4);
            float4 r2 = *(const float4*)(Bp + (size_t)(k0 + kq*4 + 2) * C_ + n4*4);
            float4 r3 = *(const float4*)(Bp + (size_t)(k0 + kq*4 + 3) * C_ + n4*4);
            ushort4 w0 = {f2bf(r0.x), f2bf(r1.x), f2bf(r2.x), f2bf(r3.x)};
            ushort4 w1 = {f2bf(r0.y), f2bf(r1.y), f2bf(r2.y), f2bf(r3.y)};
            ushort4 w2 = {f2bf(r0.z), f2bf(r1.z), f2bf(r2.z), f2bf(r3.z)};
            ushort4 w3 = {f2bf(r0.w), f2bf(r1.w), f2bf(r2.w), f2bf(r3.w)};
            *(ushort4*)&Bs[n4*4+0][kq*4] = w0;
            *(ushort4*)&Bs[n4*4+1][kq*4] = w1;
            *(ushort4*)&Bs[n4*4+2][kq*4] = w2;
            *(ushort4*)&Bs[n4*4+3][kq*4] = w3;
        }
        __syncthreads();
        int q = lane >> 4, fr = lane & 15;
        short8 a[4], b[4];
#pragma unroll
        for (int m = 0; m < 4; ++m) a[m] = *(const short8*)&As[wr + m*16 + fr][q*8];
#pragma unroll
        for (int n = 0; n < 4; ++n) b[n] = *(const short8*)&Bs[wc + n*16 + fr][q*8];
#pragma unroll
        for (int m = 0; m < 4; ++m)
#pragma unroll
            for (int n = 0; n < 4; ++n)
                acc[m][n] = __builtin_amdgcn_mfma_f32_16x16x32_bf16(a[m], b[n], acc[m][n], 0, 0, 0);
    }
    // epilogue: scatter-add weighted partial into out
    int q = lane >> 4, cfr = lane & 15;
#pragma unroll
    for (int m = 0; m < 4; ++m) {
#pragma unroll
        for (int rg = 0; rg < 4; ++rg) {
            int row = wr + m*16 + q*4 + rg;
            if (rt * BM + row < ne) {
                int grow = row0 + row;
                int tok = token_of[grow];
                float w = slotw[grow];
                float* orow = out + (size_t)tok * C_ + n0;
#pragma unroll
                for (int n = 0; n < 4; ++n)
                    atomicAdd(orow + wc + n*16 + cfr, acc[m][n][rg] * w);
            }
        }
    }
}

extern "C" void kernel_launch(void* const* d_in, const int* in_sizes, int n_in,
                              void* d_out, int out_size, void* d_ws, size_t ws_size,
                              hipStream_t stream) {
    const float* x  = (const float*)d_in[0];
    const float* Wg = (const float*)d_in[1];
    const float* W1 = (const float*)d_in[2];
    const float* W2 = (const float*)d_in[3];
    const float* W3 = (const float*)d_in[4];
    float* out = (float*)d_out;

    char* ws = (char*)d_ws;
    int*   cursors  = (int*)ws;                       // [0,32)
    int*   counts   = cursors + 8;                    // [32,64)
    int*   offsets  = counts + 8;                     // [64,96)
    int*   sel      = (int*)(ws + 128);               // NSLOT ints
    float* wts      = (float*)(ws + 128 + (size_t)NSLOT*4);
    int*   token_of = (int*)(ws + 128 + (size_t)NSLOT*8);
    float* slotw    = (float*)(ws + 128 + (size_t)NSLOT*12);
    unsigned short* Xg = (unsigned short*)(ws + 128 + (size_t)NSLOT*16);
    unsigned short* G  = (unsigned short*)(ws + 128 + (size_t)NSLOT*16 + (size_t)SPAD*C_*2);
    size_t need = 128 + (size_t)NSLOT*16 + (size_t)SPAD*C_*2 + (size_t)SPAD*H_*2;

    hipMemsetAsync(d_out, 0, (size_t)out_size * sizeof(float), stream);
    if (ws_size < need) return;   // absmax ~= max|ref| will signal ws shortage
    hipMemsetAsync(d_ws, 0, 128, stream);

    router_kernel<<<N_TOK/4, 256, 0, stream>>>(x, Wg, sel, wts, counts);
    scan_kernel<<<1, 64, 0, stream>>>(counts, offsets);
    scatter_kernel<<<NSLOT/4, 256, 0, stream>>>(x, sel, wts, offsets, cursors, token_of, slotw, Xg);
    gemm1_kernel<<<dim3(H_/BN, E_*32), 256, 0, stream>>>(Xg, W1, W3, G, counts, offsets);
    gemm2_kernel<<<dim3(C_/BN, E_*32), 256, 0, stream>>>(G, W2, out, counts, offsets, token_of, slotw);
}

// Round 2
// 537.929 us; speedup vs baseline: 2.0680x; 2.0680x over previous
//
#include <hip/hip_runtime.h>
#include <hip/hip_bf16.h>

#define E_     8
#define C_     1024
#define H_     4096
#define N_TOK  4096
#define TOPK   2
#define NSLOT  (N_TOK*TOPK)   // 8192
#define SPAD   (NSLOT+128)    // padded rows for tile-tail reads

#define BM 128
#define BN 128
#define BK 32                 // K-step (4 chunks of 8 bf16 = 16B each)
#define LPAD 40               // slow-path LDS row stride

typedef __attribute__((ext_vector_type(4))) float f32x4;
typedef __attribute__((ext_vector_type(8))) short short8;

__device__ __forceinline__ unsigned short f2bf(float f) {
    return __builtin_bit_cast(unsigned short, __float2bfloat16(f));
}

__device__ __forceinline__ void gload16(const void* g, const void* l) {
    __builtin_amdgcn_global_load_lds(
        (const __attribute__((address_space(1))) unsigned int*)g,
        (__attribute__((address_space(3))) unsigned int*)l, 16, 0, 0);
}

// ---------------- router: 1 wave per token (no atomics) ----------------
__global__ void router_kernel(const float* __restrict__ x, const float* __restrict__ Wg,
                              int* __restrict__ sel, float* __restrict__ wts) {
    int wave = (blockIdx.x * blockDim.x + threadIdx.x) >> 6;
    int lane = threadIdx.x & 63;
    if (wave >= N_TOK) return;
    const float* xr = x + (size_t)wave * C_;
    float acc[E_];
#pragma unroll
    for (int e = 0; e < E_; ++e) acc[e] = 0.f;
    for (int c = lane; c < C_; c += 64) {
        float xv = xr[c];
#pragma unroll
        for (int e = 0; e < E_; ++e) acc[e] += xv * Wg[e * C_ + c];
    }
#pragma unroll
    for (int e = 0; e < E_; ++e) {
#pragma unroll
        for (int off = 32; off > 0; off >>= 1) acc[e] += __shfl_xor(acc[e], off);
    }
    if (lane == 0) {
        float mx = acc[0];
#pragma unroll
        for (int e = 1; e < E_; ++e) mx = fmaxf(mx, acc[e]);
        float p[E_]; float s = 0.f;
#pragma unroll
        for (int e = 0; e < E_; ++e) { p[e] = __expf(acc[e] - mx); s += p[e]; }
        float inv = 1.f / s;
#pragma unroll
        for (int e = 0; e < E_; ++e) p[e] *= inv;
        int b0 = 0; float v0 = p[0];
#pragma unroll
        for (int e = 1; e < E_; ++e) if (p[e] > v0) { v0 = p[e]; b0 = e; }
        int b1 = -1; float v1 = -1.f;
#pragma unroll
        for (int e = 0; e < E_; ++e) { if (e != b0 && p[e] > v1) { v1 = p[e]; b1 = e; } }
        float isum = 1.f / (v0 + v1);
        sel[wave*2]   = b0; sel[wave*2+1] = b1;
        wts[wave*2]   = v0 * isum; wts[wave*2+1] = v1 * isum;
    }
}

// ---------------- assign: deterministic positions, single block ----------------
__global__ void assign_kernel(const int* __restrict__ sel, const float* __restrict__ wts,
                              int* __restrict__ counts, int* __restrict__ offsets,
                              int* __restrict__ pos_of_slot, int* __restrict__ token_of,
                              float* __restrict__ slotw) {
    __shared__ int cnt[256][E_];
    __shared__ int offs[E_];
    int t = threadIdx.x;
    const int PER = NSLOT / 256;   // 32
    int base = t * PER;
    int loc[E_];
#pragma unroll
    for (int e = 0; e < E_; ++e) loc[e] = 0;
    for (int i = 0; i < PER; ++i) loc[sel[base + i]]++;
#pragma unroll
    for (int e = 0; e < E_; ++e) cnt[t][e] = loc[e];
    __syncthreads();
    if (t < E_) {
        int run = 0;
        for (int i = 0; i < 256; ++i) { int c = cnt[i][t]; cnt[i][t] = run; run += c; }
        counts[t] = run;
    }
    __syncthreads();
    if (t == 0) {
        int s = 0;
        for (int e = 0; e < E_; ++e) { offs[e] = s; offsets[e] = s; s += counts[e]; }
    }
    __syncthreads();
    int run[E_];
#pragma unroll
    for (int e = 0; e < E_; ++e) run[e] = offs[e] + cnt[t][e];
    for (int i = 0; i < PER; ++i) {
        int s = base + i;
        int e = sel[s];
        int p = run[e]++;
        pos_of_slot[s] = p;
        token_of[p] = s >> 1;
        slotw[p] = wts[s];
    }
}

// ---------------- copy: gather token rows to bf16, no atomics ----------------
__global__ void copy_kernel(const float* __restrict__ x, const int* __restrict__ pos_of_slot,
                            unsigned short* __restrict__ Xg) {
    int slot = blockIdx.x * 4 + (threadIdx.x >> 6);
    int lane = threadIdx.x & 63;
    int pos = pos_of_slot[slot];
    int n = slot >> 1;
    const float* xr = x + (size_t)n * C_;
    unsigned short* dst = Xg + (size_t)pos * C_;
#pragma unroll
    for (int i = 0; i < 4; ++i) {
        int c0 = i * 256 + lane * 4;
        float4 v = *(const float4*)(xr + c0);
        ushort4 b;
        b.x = f2bf(v.x); b.y = f2bf(v.y); b.z = f2bf(v.z); b.w = f2bf(v.w);
        *(ushort4*)(dst + c0) = b;
    }
}

// ---------------- wconv: per-expert transpose fp32 [R][Cc] -> bf16 [Cc][R] ----------------
__global__ void wconv_kernel(const float* __restrict__ src, unsigned short* __restrict__ dst,
                             int R, int Cc) {
    int e = blockIdx.z;
    int c0 = blockIdx.x * 64;   // tile origin in Cc dim
    int r0 = blockIdx.y * 64;   // tile origin in R dim
    const float* s = src + (size_t)e * R * Cc;
    unsigned short* d = dst + (size_t)e * R * Cc;
    __shared__ unsigned short t_[64][72];
    int t = threadIdx.x;
    int tr = t >> 4, tc4 = (t & 15) * 4;
#pragma unroll
    for (int i = 0; i < 4; ++i) {
        int r = tr + i * 16;
        float4 v = *(const float4*)(s + (size_t)(r0 + r) * Cc + c0 + tc4);
        t_[r][tc4+0] = f2bf(v.x); t_[r][tc4+1] = f2bf(v.y);
        t_[r][tc4+2] = f2bf(v.z); t_[r][tc4+3] = f2bf(v.w);
    }
    __syncthreads();
    int oc = t >> 2, seg = (t & 3) * 16;
    short8 w0, w1;
#pragma unroll
    for (int j = 0; j < 8; ++j) {
        w0[j] = (short)t_[seg + j][oc];
        w1[j] = (short)t_[seg + 8 + j][oc];
    }
    unsigned short* dp = d + (size_t)(c0 + oc) * R + r0 + seg;
    *(short8*)dp = w0;
    *(short8*)(dp + 8) = w1;
}

// ============ FAST PATH: m97-structure GEMMs (global_load_lds, bf16 weights) ============
// LDS layout per tile: [128 rows][4 chunks of 16B], linear; chunk index XOR-swizzled
// against (row>>1)&3 via pre-swizzled GLOBAL source (both-sides involution).

__global__ __launch_bounds__(256, 2) void gemm1_fast(
        const unsigned short* __restrict__ Xg, const unsigned short* __restrict__ W1t,
        const unsigned short* __restrict__ W3t, unsigned short* __restrict__ G,
        const int* __restrict__ counts, const int* __restrict__ offsets) {
    int ct = blockIdx.x;            // col tile over H: 0..31
    int rslot = blockIdx.y;         // e*32 + rt
    int e = rslot >> 5, rt = rslot & 31;
    int ne = counts[e];
    if (rt * BM >= ne) return;
    int row0 = offsets[e] + rt * BM;
    int n0 = ct * BN;

    __shared__ unsigned short As[BM * BK];
    __shared__ unsigned short B1s[BN * BK];
    __shared__ unsigned short B3s[BN * BK];

    int tid = threadIdx.x;
    int lane = tid & 63, wid = tid >> 6;
    int wr = (wid >> 1) * 64, wc = (wid & 1) * 64;

    f32x4 acc1[4][4], acc3[4][4];
#pragma unroll
    for (int m = 0; m < 4; ++m)
#pragma unroll
        for (int n = 0; n < 4; ++n) {
            acc1[m][n] = (f32x4){0.f,0.f,0.f,0.f};
            acc3[m][n] = (f32x4){0.f,0.f,0.f,0.f};
        }

    const unsigned short* B1p = W1t + ((size_t)e * H_ + n0) * C_;
    const unsigned short* B3p = W3t + ((size_t)e * H_ + n0) * C_;

    int q = lane >> 4, fr = lane & 15;

    for (int k0 = 0; k0 < C_; k0 += BK) {
#pragma unroll
        for (int h = 0; h < 2; ++h) {
            int cid = h * 4 + wid;                 // 0..7, wave-uniform
            int row = cid * 16 + (lane >> 2);
            int kc  = (lane & 3) ^ ((row >> 1) & 3);
            gload16(Xg + (size_t)(row0 + row) * C_ + k0 + kc * 8,
                    (const char*)As + cid * 1024);
            gload16(B1p + (size_t)row * C_ + k0 + kc * 8,
                    (const char*)B1s + cid * 1024);
            gload16(B3p + (size_t)row * C_ + k0 + kc * 8,
                    (const char*)B3s + cid * 1024);
        }
        __syncthreads();   // compiler drains vmcnt before barrier
        short8 a[4], b1[4], b3[4];
#pragma unroll
        for (int m = 0; m < 4; ++m) {
            int row = wr + m * 16 + fr;
            a[m] = *(const short8*)((const char*)As + row * 64 + ((q ^ ((row >> 1) & 3)) << 4));
        }
#pragma unroll
        for (int n = 0; n < 4; ++n) {
            int row = wc + n * 16 + fr;
            int sw = (q ^ ((row >> 1) & 3)) << 4;
            b1[n] = *(const short8*)((const char*)B1s + row * 64 + sw);
            b3[n] = *(const short8*)((const char*)B3s + row * 64 + sw);
        }
#pragma unroll
        for (int m = 0; m < 4; ++m)
#pragma unroll
            for (int n = 0; n < 4; ++n) {
                acc1[m][n] = __builtin_amdgcn_mfma_f32_16x16x32_bf16(a[m], b1[n], acc1[m][n], 0, 0, 0);
                acc3[m][n] = __builtin_amdgcn_mfma_f32_16x16x32_bf16(a[m], b3[n], acc3[m][n], 0, 0, 0);
            }
        __syncthreads();   // protect LDS before next-stage overwrite
    }
    int cfr = lane & 15;
#pragma unroll
    for (int m = 0; m < 4; ++m) {
#pragma unroll
        for (int rg = 0; rg < 4; ++rg) {
            int row = wr + m * 16 + q * 4 + rg;
            if (rt * BM + row < ne) {
                size_t gbase = (size_t)(row0 + row) * H_ + n0;
#pragma unroll
                for (int n = 0; n < 4; ++n) {
                    float h1 = acc1[m][n][rg];
                    float h3 = acc3[m][n][rg];
                    float g = h1 * h3 / (1.f + __expf(-h1));
                    G[gbase + wc + n * 16 + cfr] = f2bf(g);
                }
            }
        }
    }
}

__global__ __launch_bounds__(256, 2) void gemm2_fast(
        const unsigned short* __restrict__ G, const unsigned short* __restrict__ W2t,
        float* __restrict__ out, const int* __restrict__ counts,
        const int* __restrict__ offsets, const int* __restrict__ token_of,
        const float* __restrict__ slotw) {
    int ct = blockIdx.x;            // col tile over C: 0..7
    int rslot = blockIdx.y;
    int e = rslot >> 5, rt = rslot & 31;
    int ne = counts[e];
    if (rt * BM >= ne) return;
    int row0 = offsets[e] + rt * BM;
    int n0 = ct * BN;

    __shared__ unsigned short As[BM * BK];
    __shared__ unsigned short Bs[BN * BK];

    int tid = threadIdx.x;
    int lane = tid & 63, wid = tid >> 6;
    int wr = (wid >> 1) * 64, wc = (wid & 1) * 64;

    f32x4 acc[4][4];
#pragma unroll
    for (int m = 0; m < 4; ++m)
#pragma unroll
        for (int n = 0; n < 4; ++n) acc[m][n] = (f32x4){0.f,0.f,0.f,0.f};

    const unsigned short* Bp = W2t + ((size_t)e * C_ + n0) * H_;
    int q = lane >> 4, fr = lane & 15;

    for (int k0 = 0; k0 < H_; k0 += BK) {
#pragma unroll
        for (int h = 0; h < 2; ++h) {
            int cid = h * 4 + wid;
            int row = cid * 16 + (lane >> 2);
            int kc  = (lane & 3) ^ ((row >> 1) & 3);
            gload16(G + (size_t)(row0 + row) * H_ + k0 + kc * 8,
                    (const char*)As + cid * 1024);
            gload16(Bp + (size_t)row * H_ + k0 + kc * 8,
                    (const char*)Bs + cid * 1024);
        }
        __syncthreads();
        short8 a[4], b[4];
#pragma unroll
        for (int m = 0; m < 4; ++m) {
            int row = wr + m * 16 + fr;
            a[m] = *(const short8*)((const char*)As + row * 64 + ((q ^ ((row >> 1) & 3)) << 4));
        }
#pragma unroll
        for (int n = 0; n < 4; ++n) {
            int row = wc + n * 16 + fr;
            b[n] = *(const short8*)((const char*)Bs + row * 64 + ((q ^ ((row >> 1) & 3)) << 4));
        }
#pragma unroll
        for (int m = 0; m < 4; ++m)
#pragma unroll
            for (int n = 0; n < 4; ++n)
                acc[m][n] = __builtin_amdgcn_mfma_f32_16x16x32_bf16(a[m], b[n], acc[m][n], 0, 0, 0);
        __syncthreads();
    }
    int cfr = lane & 15;
#pragma unroll
    for (int m = 0; m < 4; ++m) {
#pragma unroll
        for (int rg = 0; rg < 4; ++rg) {
            int row = wr + m * 16 + q * 4 + rg;
            if (rt * BM + row < ne) {
                int grow = row0 + row;
                int tok = token_of[grow];
                float w = slotw[grow];
                float* orow = out + (size_t)tok * C_ + n0;
#pragma unroll
                for (int n = 0; n < 4; ++n)
                    atomicAdd(orow + wc + n * 16 + cfr, acc[m][n][rg] * w);
            }
        }
    }
}

// ============ SLOW PATH (fallback if ws too small): round-1 GEMMs ============
__global__ __launch_bounds__(256, 2) void gemm1_slow(
        const unsigned short* __restrict__ Xg, const float* __restrict__ W1,
        const float* __restrict__ W3, unsigned short* __restrict__ G,
        const int* __restrict__ counts, const int* __restrict__ offsets) {
    int ct = blockIdx.x;
    int rslot = blockIdx.y;
    int e = rslot >> 5, rt = rslot & 31;
    int ne = counts[e];
    if (rt * BM >= ne) return;
    int row0 = offsets[e] + rt * BM;
    int n0 = ct * BN;

    __shared__ unsigned short As[BM][LPAD];
    __shared__ unsigned short B1s[BN][LPAD];
    __shared__ unsigned short B3s[BN][LPAD];

    int tid = threadIdx.x;
    int lane = tid & 63, wid = tid >> 6;
    int wr = (wid >> 1) * 64, wc = (wid & 1) * 64;

    f32x4 acc1[4][4], acc3[4][4];
#pragma unroll
    for (int m = 0; m < 4; ++m)
#pragma unroll
        for (int n = 0; n < 4; ++n) {
            acc1[m][n] = (f32x4){0.f,0.f,0.f,0.f};
            acc3[m][n] = (f32x4){0.f,0.f,0.f,0.f};
        }

    const float* B1p = W1 + (size_t)e * C_ * H_ + n0;
    const float* B3p = W3 + (size_t)e * C_ * H_ + n0;
    int chunk = tid & 3, rr = tid >> 2;
    int kq = tid >> 5, n4 = tid & 31;

    for (int k0 = 0; k0 < C_; k0 += BK) {
        __syncthreads();
#pragma unroll
        for (int h = 0; h < 2; ++h) {
            int row = rr + h * 64;
            uint4 v = *(const uint4*)(Xg + (size_t)(row0 + row) * C_ + k0 + chunk * 8);
            *(uint4*)&As[row][chunk * 8] = v;
        }
        {
            float4 r0 = *(const float4*)(B1p + (size_t)(k0 + kq*4 + 0) * H_ + n4*4);
            float4 r1 = *(const float4*)(B1p + (size_t)(k0 + kq*4 + 1) * H_ + n4*4);
            float4 r2 = *(const float4*)(B1p + (size_t)(k0 + kq*4 + 2) * H_ + n4*4);
            float4 r3 = *(const float4*)(B1p + (size_t)(k0 + kq*4 + 3) * H_ + n4*4);
            ushort4 w0 = {f2bf(r0.x), f2bf(r1.x), f2bf(r2.x), f2bf(r3.x)};
            ushort4 w1 = {f2bf(r0.y), f2bf(r1.y), f2bf(r2.y), f2bf(r3.y)};
            ushort4 w2 = {f2bf(r0.z), f2bf(r1.z), f2bf(r2.z), f2bf(r3.z)};
            ushort4 w3 = {f2bf(r0.w), f2bf(r1.w), f2bf(r2.w), f2bf(r3.w)};
            *(ushort4*)&B1s[n4*4+0][kq*4] = w0;
            *(ushort4*)&B1s[n4*4+1][kq*4] = w1;
            *(ushort4*)&B1s[n4*4+2][kq*4] = w2;
            *(ushort4*)&B1s[n4*4+3][kq*4] = w3;
            r0 = *(const float4*)(B3p + (size_t)(k0 + kq*4 + 0) * H_ + n4*4);
            r1 = *(const float4*)(B3p + (size_t)(k0 + kq*4 + 1) * H_ + n4*4);
            r2 = *(const float4*)(B3p + (size_t)(k0 + kq*4 + 2) * H_ + n4*4);
            r3 = *(const float4*)(B3p + (size_t)(k0 + kq*4 + 3) * H_ + n4*4);
            w0 = (ushort4){f2bf(r0.x), f2bf(r1.x), f2bf(r2.x), f2bf(r3.x)};
            w1 = (ushort4){f2bf(r0.y), f2bf(r1.y), f2bf(r2.y), f2bf(r3.y)};
            w2 = (ushort4){f2bf(r0.z), f2bf(r1.z), f2bf(r2.z), f2bf(r3.z)};
            w3 = (ushort4){f2bf(r0.w), f2bf(r1.w), f2bf(r2.w), f2bf(r3.w)};
            *(ushort4*)&B3s[n4*4+0][kq*4] = w0;
            *(ushort4*)&B3s[n4*4+1][kq*4] = w1;
            *(ushort4*)&B3s[n4*4+2][kq*4] = w2;
            *(ushort4*)&B3s[n4*4+3][kq*4] = w3;
        }
        __syncthreads();
        int q = lane >> 4, fr = lane & 15;
        short8 a[4], b1[4], b3[4];
#pragma unroll
        for (int m = 0; m < 4; ++m) a[m] = *(const short8*)&As[wr + m*16 + fr][q*8];
#pragma unroll
        for (int n = 0; n < 4; ++n) {
            b1[n] = *(const short8*)&B1s[wc + n*16 + fr][q*8];
            b3[n] = *(const short8*)&B3s[wc + n*16 + fr][q*8];
        }
#pragma unroll
        for (int m = 0; m < 4; ++m)
#pragma unroll
            for (int n = 0; n < 4; ++n) {
                acc1[m][n] = __builtin_amdgcn_mfma_f32_16x16x32_bf16(a[m], b1[n], acc1[m][n], 0, 0, 0);
                acc3[m][n] = __builtin_amdgcn_mfma_f32_16x16x32_bf16(a[m], b3[n], acc3[m][n], 0, 0, 0);
            }
    }
    int q = lane >> 4, cfr = lane & 15;
#pragma unroll
    for (int m = 0; m < 4; ++m) {
#pragma unroll
        for (int rg = 0; rg < 4; ++rg) {
            int row = wr + m*16 + q*4 + rg;
            if (rt * BM + row < ne) {
                size_t gbase = (size_t)(row0 + row) * H_ + n0;
#pragma unroll
                for (int n = 0; n < 4; ++n) {
                    float h1 = acc1[m][n][rg];
                    float h3 = acc3[m][n][rg];
                    float g = h1 * h3 / (1.f + __expf(-h1));
                    G[gbase + wc + n*16 + cfr] = f2bf(g);
                }
            }
        }
    }
}

__global__ __launch_bounds__(256, 2) void gemm2_slow(
        const unsigned short* __restrict__ G, const float* __restrict__ W2,
        float* __restrict__ out, const int* __restrict__ counts,
        const int* __restrict__ offsets, const int* __restrict__ token_of,
        const float* __restrict__ slotw) {
    int ct = blockIdx.x;
    int rslot = blockIdx.y;
    int e = rslot >> 5, rt = rslot & 31;
    int ne = counts[e];
    if (rt * BM >= ne) return;
    int row0 = offsets[e] + rt * BM;
    int n0 = ct * BN;

    __shared__ unsigned short As[BM][LPAD];
    __shared__ unsigned short Bs[BN][LPAD];

    int tid = threadIdx.x;
    int lane = tid & 63, wid = tid >> 6;
    int wr = (wid >> 1) * 64, wc = (wid & 1) * 64;

    f32x4 acc[4][4];
#pragma unroll
    for (int m = 0; m < 4; ++m)
#pragma unroll
        for (int n = 0; n < 4; ++n) acc[m][n] = (f32x4){0.f,0.f,0.f,0.f};

    const float* Bp = W2 + (size_t)e * H_ * C_ + n0;
    int chunk = tid & 3, rr = tid >> 2;
    int kq = tid >> 5, n4 = tid & 31;

    for (int k0 = 0; k0 < H_; k0 += BK) {
        __syncthreads();
#pragma unroll
        for (int h = 0; h < 2; ++h) {
            int row = rr + h * 64;
            uint4 v = *(const uint4*)(G + (size_t)(row0 + row) * H_ + k0 + chunk * 8);
            *(uint4*)&As[row][chunk * 8] = v;
        }
        {
            float4 r0 = *(const float4*)(Bp + (size_t)(k0 + kq*4 + 0) * C_ + n4*4);
            float4 r1 = *(const float4*)(Bp + (size_t)(k0 + kq*4 + 1) * C_ + n4*4);
            float4 r2 = *(const float4*)(Bp + (size_t)(k0 + kq*4 + 2) * C_ + n4*4);
            float4 r3 = *(const float4*)(Bp + (size_t)(k0 + kq*4 + 3) * C_ + n4*4);
            ushort4 w0 = {f2bf(r0.x), f2bf(r1.x), f2bf(r2.x), f2bf(r3.x)};
            ushort4 w1 = {f2bf(r0.y), f2bf(r1.y), f2bf(r2.y), f2bf(r3.y)};
            ushort4 w2 = {f2bf(r0.z), f2bf(r1.z), f2bf(r2.z), f2bf(r3.z)};
            ushort4 w3 = {f2bf(r0.w), f2bf(r1.w), f2bf(r2.w), f2bf(r3.w)};
            *(ushort4*)&Bs[n4*4+0][kq*4] = w0;
            *(ushort4*)&Bs[n4*4+1][kq*4] = w1;
            *(ushort4*)&Bs[n4*4+2][kq*4] = w2;
            *(ushort4*)&Bs[n4*4+3][kq*4] = w3;
        }
        __syncthreads();
        int q = lane >> 4, fr = lane & 15;
        short8 a[4], b[4];
#pragma unroll
        for (int m = 0; m < 4; ++m) a[m] = *(const short8*)&As[wr + m*16 + fr][q*8];
#pragma unroll
        for (int n = 0; n < 4; ++n) b[n] = *(const short8*)&Bs[wc + n*16 + fr][q*8];
#pragma unroll
        for (int m = 0; m < 4; ++m)
#pragma unroll
            for (int n = 0; n < 4; ++n)
                acc[m][n] = __builtin_amdgcn_mfma_f32_16x16x32_bf16(a[m], b[n], acc[m][n], 0, 0, 0);
    }
    int q = lane >> 4, cfr = lane & 15;
#pragma unroll
    for (int m = 0; m < 4; ++m) {
#pragma unroll
        for (int rg = 0; rg < 4; ++rg) {
            int row = wr + m*16 + q*4 + rg;
            if (rt * BM + row < ne) {
                int grow = row0 + row;
                int tok = token_of[grow];
                float w = slotw[grow];
                float* orow = out + (size_t)tok * C_ + n0;
#pragma unroll
                for (int n = 0; n < 4; ++n)
                    atomicAdd(orow + wc + n*16 + cfr, acc[m][n][rg] * w);
            }
        }
    }
}

extern "C" void kernel_launch(void* const* d_in, const int* in_sizes, int n_in,
                              void* d_out, int out_size, void* d_ws, size_t ws_size,
                              hipStream_t stream) {
    const float* x  = (const float*)d_in[0];
    const float* Wg = (const float*)d_in[1];
    const float* W1 = (const float*)d_in[2];
    const float* W2 = (const float*)d_in[3];
    const float* W3 = (const float*)d_in[4];
    float* out = (float*)d_out;

    char* ws = (char*)d_ws;
    size_t o = 0;
    int*   sel      = (int*)(ws + o);  o += (size_t)NSLOT * 4;
    float* wts      = (float*)(ws + o); o += (size_t)NSLOT * 4;
    int*   pos      = (int*)(ws + o);  o += (size_t)NSLOT * 4;
    int*   token_of = (int*)(ws + o);  o += (size_t)NSLOT * 4;
    float* slotw    = (float*)(ws + o); o += (size_t)NSLOT * 4;
    int*   counts   = (int*)(ws + o);
    int*   offsets  = counts + E_;     o += 256;
    unsigned short* Xg = (unsigned short*)(ws + o); o += (size_t)SPAD * C_ * 2;
    unsigned short* G  = (unsigned short*)(ws + o); o += (size_t)SPAD * H_ * 2;
    size_t need_slow = o;
    unsigned short* W1t = (unsigned short*)(ws + o); o += (size_t)E_ * H_ * C_ * 2;
    unsigned short* W3t = (unsigned short*)(ws + o); o += (size_t)E_ * H_ * C_ * 2;
    unsigned short* W2t = W1t;   // W1t region freed after gemm1
    size_t need_fast = o;

    hipMemsetAsync(d_out, 0, (size_t)out_size * sizeof(float), stream);
    if (ws_size < need_slow) return;

    router_kernel<<<N_TOK/4, 256, 0, stream>>>(x, Wg, sel, wts);
    assign_kernel<<<1, 256, 0, stream>>>(sel, wts, counts, offsets, pos, token_of, slotw);
    copy_kernel<<<NSLOT/4, 256, 0, stream>>>(x, pos, Xg);

    if (ws_size >= need_fast) {
        wconv_kernel<<<dim3(H_/64, C_/64, E_), 256, 0, stream>>>(W1, W1t, C_, H_);
        wconv_kernel<<<dim3(H_/64, C_/64, E_), 256, 0, stream>>>(W3, W3t, C_, H_);
        gemm1_fast<<<dim3(H_/BN, E_*32), 256, 0, stream>>>(Xg, W1t, W3t, G, counts, offsets);
        wconv_kernel<<<dim3(C_/64, H_/64, E_), 256, 0, stream>>>(W2, W2t, H_, C_);
        gemm2_fast<<<dim3(C_/BN, E_*32), 256, 0, stream>>>(G, W2t, out, counts, offsets, token_of, slotw);
    } else {
        gemm1_slow<<<dim3(H_/BN, E_*32), 256, 0, stream>>>(Xg, W1, W3, G, counts, offsets);
        gemm2_slow<<<dim3(C_/BN, E_*32), 256, 0, stream>>>(G, W2, out, counts, offsets, token_of, slotw);
    }
}

// Round 4
// 487.532 us; speedup vs baseline: 2.2818x; 1.1034x over previous
//
#include <hip/hip_runtime.h>
#include <hip/hip_bf16.h>

#define E_     8
#define C_     1024
#define H_     4096
#define N_TOK  4096
#define TOPK   2
#define NSLOT  (N_TOK*TOPK)   // 8192
#define SPAD   (NSLOT+128)    // padded rows for tile-tail reads

#define LPAD 40               // slow-path LDS row stride

typedef __attribute__((ext_vector_type(4))) float f32x4;
typedef __attribute__((ext_vector_type(8))) short short8;

__device__ __forceinline__ unsigned short f2bf(float f) {
    return __builtin_bit_cast(unsigned short, __float2bfloat16(f));
}

__device__ __forceinline__ void gload16(const void* g, const void* l) {
    __builtin_amdgcn_global_load_lds(
        (const __attribute__((address_space(1))) unsigned int*)g,
        (__attribute__((address_space(3))) unsigned int*)l, 16, 0, 0);
}

#define WAITVM_(n) asm volatile("s_waitcnt vmcnt(" #n ")" ::: "memory")
#define WAITVM(n) WAITVM_(n)

// ---------------- router: 1 wave per token (no atomics) ----------------
__global__ void router_kernel(const float* __restrict__ x, const float* __restrict__ Wg,
                              int* __restrict__ sel, float* __restrict__ wts) {
    int wave = (blockIdx.x * blockDim.x + threadIdx.x) >> 6;
    int lane = threadIdx.x & 63;
    if (wave >= N_TOK) return;
    const float* xr = x + (size_t)wave * C_;
    float acc[E_];
#pragma unroll
    for (int e = 0; e < E_; ++e) acc[e] = 0.f;
    for (int c = lane; c < C_; c += 64) {
        float xv = xr[c];
#pragma unroll
        for (int e = 0; e < E_; ++e) acc[e] += xv * Wg[e * C_ + c];
    }
#pragma unroll
    for (int e = 0; e < E_; ++e) {
#pragma unroll
        for (int off = 32; off > 0; off >>= 1) acc[e] += __shfl_xor(acc[e], off);
    }
    if (lane == 0) {
        float mx = acc[0];
#pragma unroll
        for (int e = 1; e < E_; ++e) mx = fmaxf(mx, acc[e]);
        float p[E_]; float s = 0.f;
#pragma unroll
        for (int e = 0; e < E_; ++e) { p[e] = __expf(acc[e] - mx); s += p[e]; }
        float inv = 1.f / s;
#pragma unroll
        for (int e = 0; e < E_; ++e) p[e] *= inv;
        int b0 = 0; float v0 = p[0];
#pragma unroll
        for (int e = 1; e < E_; ++e) if (p[e] > v0) { v0 = p[e]; b0 = e; }
        int b1 = -1; float v1 = -1.f;
#pragma unroll
        for (int e = 0; e < E_; ++e) { if (e != b0 && p[e] > v1) { v1 = p[e]; b1 = e; } }
        float isum = 1.f / (v0 + v1);
        sel[wave*2]   = b0; sel[wave*2+1] = b1;
        wts[wave*2]   = v0 * isum; wts[wave*2+1] = v1 * isum;
    }
}

// ---------------- assign: deterministic positions, single block ----------------
__global__ void assign_kernel(const int* __restrict__ sel, const float* __restrict__ wts,
                              int* __restrict__ counts, int* __restrict__ offsets,
                              int* __restrict__ pos_of_slot, int* __restrict__ token_of,
                              float* __restrict__ slotw) {
    __shared__ int cnt[256][E_];
    __shared__ int offs[E_];
    int t = threadIdx.x;
    const int PER = NSLOT / 256;   // 32
    int base = t * PER;
    int loc[E_];
#pragma unroll
    for (int e = 0; e < E_; ++e) loc[e] = 0;
    for (int i = 0; i < PER; ++i) loc[sel[base + i]]++;
#pragma unroll
    for (int e = 0; e < E_; ++e) cnt[t][e] = loc[e];
    __syncthreads();
    if (t < E_) {
        int run = 0;
        for (int i = 0; i < 256; ++i) { int c = cnt[i][t]; cnt[i][t] = run; run += c; }
        counts[t] = run;
    }
    __syncthreads();
    if (t == 0) {
        int s = 0;
        for (int e = 0; e < E_; ++e) { offs[e] = s; offsets[e] = s; s += counts[e]; }
    }
    __syncthreads();
    int run[E_];
#pragma unroll
    for (int e = 0; e < E_; ++e) run[e] = offs[e] + cnt[t][e];
    for (int i = 0; i < PER; ++i) {
        int s = base + i;
        int e = sel[s];
        int p = run[e]++;
        pos_of_slot[s] = p;
        token_of[p] = s >> 1;
        slotw[p] = wts[s];
    }
}

// ---------------- copy: gather token rows to bf16 ----------------
__global__ void copy_kernel(const float* __restrict__ x, const int* __restrict__ pos_of_slot,
                            unsigned short* __restrict__ Xg) {
    int slot = blockIdx.x * 4 + (threadIdx.x >> 6);
    int lane = threadIdx.x & 63;
    int pos = pos_of_slot[slot];
    int n = slot >> 1;
    const float* xr = x + (size_t)n * C_;
    unsigned short* dst = Xg + (size_t)pos * C_;
#pragma unroll
    for (int i = 0; i < 4; ++i) {
        int c0 = i * 256 + lane * 4;
        float4 v = *(const float4*)(xr + c0);
        ushort4 b;
        b.x = f2bf(v.x); b.y = f2bf(v.y); b.z = f2bf(v.z); b.w = f2bf(v.w);
        *(ushort4*)(dst + c0) = b;
    }
}

// ---------------- wconv: per-expert transpose fp32 [R][Cc] -> bf16 [Cc][R] ----------------
__global__ void wconv_kernel(const float* __restrict__ src, unsigned short* __restrict__ dst,
                             int R, int Cc) {
    int e = blockIdx.z;
    int c0 = blockIdx.x * 64;
    int r0 = blockIdx.y * 64;
    const float* s = src + (size_t)e * R * Cc;
    unsigned short* d = dst + (size_t)e * R * Cc;
    __shared__ unsigned short t_[64][72];
    int t = threadIdx.x;
    int tr = t >> 4, tc4 = (t & 15) * 4;
#pragma unroll
    for (int i = 0; i < 4; ++i) {
        int r = tr + i * 16;
        float4 v = *(const float4*)(s + (size_t)(r0 + r) * Cc + c0 + tc4);
        t_[r][tc4+0] = f2bf(v.x); t_[r][tc4+1] = f2bf(v.y);
        t_[r][tc4+2] = f2bf(v.z); t_[r][tc4+3] = f2bf(v.w);
    }
    __syncthreads();
    int oc = t >> 2, seg = (t & 3) * 16;
    short8 w0, w1;
#pragma unroll
    for (int j = 0; j < 8; ++j) {
        w0[j] = (short)t_[seg + j][oc];
        w1[j] = (short)t_[seg + 8 + j][oc];
    }
    unsigned short* dp = d + (size_t)(c0 + oc) * R + r0 + seg;
    *(short8*)dp = w0;
    *(short8*)(dp + 8) = w1;
}

// ============ deep-pipelined GEMMs: 256x128 tile, BK=64, 8 waves, dbuf LDS ============
// 4 phases/K-tile: {barrier; stage 1 unit of tile tsrc=min(t+1,NT-1) (UNCONDITIONAL, so
// the vmcnt ledger is issue-invariant incl. last tile); counted vmcnt (never 0 in loop);
// barrier; ds_read frags; setprio(1); MFMA; setprio(0)}
// chunk swizzle: 128B rows of 8x16B chunks, phys = logical ^ (row&7), applied on global
// source AND ds_read (both-sides involution); gload_lds dest stays linear.

#define G1_BM 256
#define G1_BN 128
#define G1_BK 64
#define G1_NT (C_/G1_BK)   // 16

#define G1_PHASE(F, ACCX, WN)                                                       \
  {                                                                                 \
    __builtin_amdgcn_s_barrier();                                                   \
    {                                                                               \
      int pn = (t + 1) & 1;                                                         \
      int tsrc = (t + 1 < G1_NT) ? (t + 1) : t;                                     \
      int k0n = tsrc * G1_BK;                                                       \
      if ((F) == 0 || (F) == 1) {                                                   \
        _Pragma("unroll")                                                           \
        for (int r = 0; r < 2; ++r) {                                               \
          int row = (F)*128 + r*64 + srow;                                          \
          int lch = pch ^ (row & 7);                                                \
          gload16(Ap + (size_t)row * C_ + k0n + lch*8,                              \
                  (char*)As + pn*32768 + (((F)*128 + r*64 + wid*8) << 7));          \
        }                                                                           \
      } else {                                                                      \
        const unsigned short* gsrc = ((F) == 2) ? B1p : B3p;                        \
        char* ldst = (char*)(((F) == 2) ? B1s : B3s) + pn*16384;                    \
        _Pragma("unroll")                                                           \
        for (int r = 0; r < 2; ++r) {                                               \
          int row = r*64 + srow;                                                    \
          int lch = pch ^ (row & 7);                                                \
          gload16(gsrc + (size_t)row * C_ + k0n + lch*8,                            \
                  ldst + ((r*64 + wid*8) << 7));                                    \
        }                                                                           \
      }                                                                             \
    }                                                                               \
    WAITVM(WN);                                                                     \
    __builtin_amdgcn_s_barrier();                                                   \
    __builtin_amdgcn_sched_barrier(0);                                              \
    {                                                                               \
      int p = t & 1; int ks = (F) & 1;                                              \
      const unsigned short* Ab = As + p*16384;                                      \
      const unsigned short* Bb = (((F) < 2) ? B1s : B3s) + p*8192;                  \
      short8 a[4], b[4];                                                            \
      _Pragma("unroll")                                                             \
      for (int m = 0; m < 4; ++m) {                                                 \
        int row = wm*64 + m*16 + fr;                                                \
        a[m] = *(const short8*)(Ab + row*64 + (((ks*4 + q) ^ (row & 7)) << 3));     \
      }                                                                             \
      _Pragma("unroll")                                                             \
      for (int n = 0; n < 4; ++n) {                                                 \
        int row = wn*64 + n*16 + fr;                                                \
        b[n] = *(const short8*)(Bb + row*64 + (((ks*4 + q) ^ (row & 7)) << 3));     \
      }                                                                             \
      __builtin_amdgcn_s_setprio(1);                                                \
      _Pragma("unroll")                                                             \
      for (int m = 0; m < 4; ++m)                                                   \
        _Pragma("unroll")                                                           \
        for (int n = 0; n < 4; ++n)                                                 \
          ACCX[m][n] = __builtin_amdgcn_mfma_f32_16x16x32_bf16(a[m], b[n], ACCX[m][n], 0, 0, 0); \
      __builtin_amdgcn_s_setprio(0);                                                \
    }                                                                               \
  }

__global__ __launch_bounds__(512, 2) void gemm1_f8(
        const unsigned short* __restrict__ Xg, const unsigned short* __restrict__ W1t,
        const unsigned short* __restrict__ W3t, unsigned short* __restrict__ G,
        const int* __restrict__ counts, const int* __restrict__ offsets) {
    int ct = blockIdx.x;            // H/128 = 32
    int rslot = blockIdx.y;         // e*32 + rt
    int e = rslot >> 5, rt = rslot & 31;
    int ne = counts[e];
    if (rt * G1_BM >= ne) return;
    int row0 = offsets[e] + rt * G1_BM;
    int n0 = ct * G1_BN;

    extern __shared__ unsigned short lds[];
    unsigned short* As  = lds;                 // [2][256*64]  64KB
    unsigned short* B1s = lds + 2*256*64;      // [2][128*64]  32KB
    unsigned short* B3s = B1s + 2*128*64;      // [2][128*64]  32KB

    int tid = threadIdx.x, lane = tid & 63, wid = tid >> 6;
    int wm = wid >> 1, wn = wid & 1;
    int fr = lane & 15, q = lane >> 4;
    int srow = wid * 8 + (lane >> 3);
    int pch  = lane & 7;

    const unsigned short* Ap  = Xg + (size_t)row0 * C_;
    const unsigned short* B1p = W1t + ((size_t)e * H_ + n0) * C_;
    const unsigned short* B3p = W3t + ((size_t)e * H_ + n0) * C_;

    f32x4 acc1[4][4], acc3[4][4];
#pragma unroll
    for (int m = 0; m < 4; ++m)
#pragma unroll
        for (int n = 0; n < 4; ++n) {
            acc1[m][n] = (f32x4){0.f,0.f,0.f,0.f};
            acc3[m][n] = (f32x4){0.f,0.f,0.f,0.f};
        }

    // prologue: stage K-tile 0 (order: A0, A1, B1, B3) into buffer 0
#pragma unroll
    for (int u = 0; u < 2; ++u)
#pragma unroll
        for (int r = 0; r < 2; ++r) {
            int row = u*128 + r*64 + srow;
            int lch = pch ^ (row & 7);
            gload16(Ap + (size_t)row * C_ + lch*8,
                    (char*)As + ((u*128 + r*64 + wid*8) << 7));
        }
#pragma unroll
    for (int r = 0; r < 2; ++r) {
        int row = r*64 + srow;
        int lch = pch ^ (row & 7);
        gload16(B1p + (size_t)row * C_ + lch*8, (char*)B1s + ((r*64 + wid*8) << 7));
    }
#pragma unroll
    for (int r = 0; r < 2; ++r) {
        int row = r*64 + srow;
        int lch = pch ^ (row & 7);
        gload16(B3p + (size_t)row * C_ + lch*8, (char*)B3s + ((r*64 + wid*8) << 7));
    }

    for (int t = 0; t < G1_NT; ++t) {
        G1_PHASE(0, acc1, 4)
        G1_PHASE(1, acc1, 6)
        G1_PHASE(2, acc3, 6)
        G1_PHASE(3, acc3, 8)
    }
    WAITVM(0);   // drain dummy last-tile staging before kernel end

    int cfr = lane & 15;
#pragma unroll
    for (int m = 0; m < 4; ++m)
#pragma unroll
        for (int rg = 0; rg < 4; ++rg) {
            int row = wm*64 + m*16 + q*4 + rg;
            if (rt * G1_BM + row < ne) {
                size_t gbase = (size_t)(row0 + row) * H_ + n0 + wn*64;
#pragma unroll
                for (int n = 0; n < 4; ++n) {
                    float h1 = acc1[m][n][rg];
                    float h3 = acc3[m][n][rg];
                    float g = h1 * h3 / (1.f + __expf(-h1));
                    G[gbase + n*16 + cfr] = f2bf(g);
                }
            }
        }
}

#define G2_BM 256
#define G2_BN 128
#define G2_BK 64
#define G2_NT (H_/G2_BK)   // 64

// phases: F = ks*2 + nh; stage: F0->A0(next), F1->A1(next), F2->B(next), F3->none
#define G2_PHASE(F, WN)                                                             \
  {                                                                                 \
    __builtin_amdgcn_s_barrier();                                                   \
    if ((F) < 3) {                                                                  \
      int pn = (t + 1) & 1;                                                         \
      int tsrc = (t + 1 < G2_NT) ? (t + 1) : t;                                     \
      int k0n = tsrc * G2_BK;                                                       \
      if ((F) == 0 || (F) == 1) {                                                   \
        _Pragma("unroll")                                                           \
        for (int r = 0; r < 2; ++r) {                                               \
          int row = (F)*128 + r*64 + srow;                                          \
          int lch = pch ^ (row & 7);                                                \
          gload16(Ap + (size_t)row * H_ + k0n + lch*8,                              \
                  (char*)As + pn*32768 + (((F)*128 + r*64 + wid*8) << 7));          \
        }                                                                           \
      } else {                                                                      \
        _Pragma("unroll")                                                           \
        for (int r = 0; r < 2; ++r) {                                               \
          int row = r*64 + srow;                                                    \
          int lch = pch ^ (row & 7);                                                \
          gload16(Bp + (size_t)row * H_ + k0n + lch*8,                              \
                  (char*)Bs + pn*16384 + ((r*64 + wid*8) << 7));                    \
        }                                                                           \
      }                                                                             \
    }                                                                               \
    WAITVM(WN);                                                                     \
    __builtin_amdgcn_s_barrier();                                                   \
    __builtin_amdgcn_sched_barrier(0);                                              \
    {                                                                               \
      int p = t & 1; int ks = (F) >> 1; int nh = (F) & 1;                           \
      const unsigned short* Ab = As + p*16384;                                      \
      const unsigned short* Bb = Bs + p*8192;                                       \
      short8 a[4], b[2];                                                            \
      _Pragma("unroll")                                                             \
      for (int m = 0; m < 4; ++m) {                                                 \
        int row = wm*64 + m*16 + fr;                                                \
        a[m] = *(const short8*)(Ab + row*64 + (((ks*4 + q) ^ (row & 7)) << 3));     \
      }                                                                             \
      _Pragma("unroll")                                                             \
      for (int j = 0; j < 2; ++j) {                                                 \
        int row = wn*64 + (nh*2 + j)*16 + fr;                                       \
        b[j] = *(const short8*)(Bb + row*64 + (((ks*4 + q) ^ (row & 7)) << 3));     \
      }                                                                             \
      __builtin_amdgcn_s_setprio(1);                                                \
      _Pragma("unroll")                                                             \
      for (int m = 0; m < 4; ++m)                                                   \
        _Pragma("unroll")                                                           \
        for (int j = 0; j < 2; ++j)                                                 \
          acc[m][nh*2 + j] = __builtin_amdgcn_mfma_f32_16x16x32_bf16(a[m], b[j], acc[m][nh*2 + j], 0, 0, 0); \
      __builtin_amdgcn_s_setprio(0);                                                \
    }                                                                               \
  }

__global__ __launch_bounds__(512, 2) void gemm2_f8(
        const unsigned short* __restrict__ G, const unsigned short* __restrict__ W2t,
        float* __restrict__ out, const int* __restrict__ counts,
        const int* __restrict__ offsets, const int* __restrict__ token_of,
        const float* __restrict__ slotw) {
    int ct = blockIdx.x;            // C/128 = 8
    int rslot = blockIdx.y;
    int e = rslot >> 5, rt = rslot & 31;
    int ne = counts[e];
    if (rt * G2_BM >= ne) return;
    int row0 = offsets[e] + rt * G2_BM;
    int n0 = ct * G2_BN;

    extern __shared__ unsigned short lds[];
    unsigned short* As = lds;                  // [2][256*64]  64KB
    unsigned short* Bs = lds + 2*256*64;       // [2][128*64]  32KB

    int tid = threadIdx.x, lane = tid & 63, wid = tid >> 6;
    int wm = wid >> 1, wn = wid & 1;
    int fr = lane & 15, q = lane >> 4;
    int srow = wid * 8 + (lane >> 3);
    int pch  = lane & 7;

    const unsigned short* Ap = G + (size_t)row0 * H_;
    const unsigned short* Bp = W2t + ((size_t)e * C_ + n0) * H_;

    f32x4 acc[4][4];
#pragma unroll
    for (int m = 0; m < 4; ++m)
#pragma unroll
        for (int n = 0; n < 4; ++n) acc[m][n] = (f32x4){0.f,0.f,0.f,0.f};

    // prologue: stage K-tile 0 (A0, A1, B) into buffer 0
#pragma unroll
    for (int u = 0; u < 2; ++u)
#pragma unroll
        for (int r = 0; r < 2; ++r) {
            int row = u*128 + r*64 + srow;
            int lch = pch ^ (row & 7);
            gload16(Ap + (size_t)row * H_ + lch*8,
                    (char*)As + ((u*128 + r*64 + wid*8) << 7));
        }
#pragma unroll
    for (int r = 0; r < 2; ++r) {
        int row = r*64 + srow;
        int lch = pch ^ (row & 7);
        gload16(Bp + (size_t)row * H_ + lch*8, (char*)Bs + ((r*64 + wid*8) << 7));
    }

    for (int t = 0; t < G2_NT; ++t) {
        G2_PHASE(0, 2)
        G2_PHASE(1, 4)
        G2_PHASE(2, 6)
        G2_PHASE(3, 6)
    }
    WAITVM(0);   // drain dummy last-tile staging before kernel end

    int cfr = lane & 15;
#pragma unroll
    for (int m = 0; m < 4; ++m)
#pragma unroll
        for (int rg = 0; rg < 4; ++rg) {
            int row = wm*64 + m*16 + q*4 + rg;
            if (rt * G2_BM + row < ne) {
                int grow = row0 + row;
                int tok = token_of[grow];
                float w = slotw[grow];
                float* orow = out + (size_t)tok * C_ + n0 + wn*64;
#pragma unroll
                for (int n = 0; n < 4; ++n)
                    atomicAdd(orow + n*16 + cfr, acc[m][n][rg] * w);
            }
        }
}

// ============ SLOW PATH (fallback if ws too small) ============
#define BM 128
#define BN 128
#define BK 32
__global__ __launch_bounds__(256, 2) void gemm1_slow(
        const unsigned short* __restrict__ Xg, const float* __restrict__ W1,
        const float* __restrict__ W3, unsigned short* __restrict__ G,
        const int* __restrict__ counts, const int* __restrict__ offsets) {
    int ct = blockIdx.x;
    int rslot = blockIdx.y;
    int e = rslot >> 5, rt = rslot & 31;
    int ne = counts[e];
    if (rt * BM >= ne) return;
    int row0 = offsets[e] + rt * BM;
    int n0 = ct * BN;

    __shared__ unsigned short As[BM][LPAD];
    __shared__ unsigned short B1s[BN][LPAD];
    __shared__ unsigned short B3s[BN][LPAD];

    int tid = threadIdx.x;
    int lane = tid & 63, wid = tid >> 6;
    int wr = (wid >> 1) * 64, wc = (wid & 1) * 64;

    f32x4 acc1[4][4], acc3[4][4];
#pragma unroll
    for (int m = 0; m < 4; ++m)
#pragma unroll
        for (int n = 0; n < 4; ++n) {
            acc1[m][n] = (f32x4){0.f,0.f,0.f,0.f};
            acc3[m][n] = (f32x4){0.f,0.f,0.f,0.f};
        }

    const float* B1p = W1 + (size_t)e * C_ * H_ + n0;
    const float* B3p = W3 + (size_t)e * C_ * H_ + n0;
    int chunk = tid & 3, rr = tid >> 2;
    int kq = tid >> 5, n4 = tid & 31;

    for (int k0 = 0; k0 < C_; k0 += BK) {
        __syncthreads();
#pragma unroll
        for (int h = 0; h < 2; ++h) {
            int row = rr + h * 64;
            uint4 v = *(const uint4*)(Xg + (size_t)(row0 + row) * C_ + k0 + chunk * 8);
            *(uint4*)&As[row][chunk * 8] = v;
        }
        {
            float4 r0 = *(const float4*)(B1p + (size_t)(k0 + kq*4 + 0) * H_ + n4*4);
            float4 r1 = *(const float4*)(B1p + (size_t)(k0 + kq*4 + 1) * H_ + n4*4);
            float4 r2 = *(const float4*)(B1p + (size_t)(k0 + kq*4 + 2) * H_ + n4*4);
            float4 r3 = *(const float4*)(B1p + (size_t)(k0 + kq*4 + 3) * H_ + n4*4);
            ushort4 w0 = {f2bf(r0.x), f2bf(r1.x), f2bf(r2.x), f2bf(r3.x)};
            ushort4 w1 = {f2bf(r0.y), f2bf(r1.y), f2bf(r2.y), f2bf(r3.y)};
            ushort4 w2 = {f2bf(r0.z), f2bf(r1.z), f2bf(r2.z), f2bf(r3.z)};
            ushort4 w3 = {f2bf(r0.w), f2bf(r1.w), f2bf(r2.w), f2bf(r3.w)};
            *(ushort4*)&B1s[n4*4+0][kq*4] = w0;
            *(ushort4*)&B1s[n4*4+1][kq*4] = w1;
            *(ushort4*)&B1s[n4*4+2][kq*4] = w2;
            *(ushort4*)&B1s[n4*4+3][kq*4] = w3;
            r0 = *(const float4*)(B3p + (size_t)(k0 + kq*4 + 0) * H_ + n4*4);
            r1 = *(const float4*)(B3p + (size_t)(k0 + kq*4 + 1) * H_ + n4*4);
            r2 = *(const float4*)(B3p + (size_t)(k0 + kq*4 + 2) * H_ + n4*4);
            r3 = *(const float4*)(B3p + (size_t)(k0 + kq*4 + 3) * H_ + n4*4);
            w0 = (ushort4){f2bf(r0.x), f2bf(r1.x), f2bf(r2.x), f2bf(r3.x)};
            w1 = (ushort4){f2bf(r0.y), f2bf(r1.y), f2bf(r2.y), f2bf(r3.y)};
            w2 = (ushort4){f2bf(r0.z), f2bf(r1.z), f2bf(r2.z), f2bf(r3.z)};
            w3 = (ushort4){f2bf(r0.w), f2bf(r1.w), f2bf(r2.w), f2bf(r3.w)};
            *(ushort4*)&B3s[n4*4+0][kq*4] = w0;
            *(ushort4*)&B3s[n4*4+1][kq*4] = w1;
            *(ushort4*)&B3s[n4*4+2][kq*4] = w2;
            *(ushort4*)&B3s[n4*4+3][kq*4] = w3;
        }
        __syncthreads();
        int q = lane >> 4, fr = lane & 15;
        short8 a[4], b1[4], b3[4];
#pragma unroll
        for (int m = 0; m < 4; ++m) a[m] = *(const short8*)&As[wr + m*16 + fr][q*8];
#pragma unroll
        for (int n = 0; n < 4; ++n) {
            b1[n] = *(const short8*)&B1s[wc + n*16 + fr][q*8];
            b3[n] = *(const short8*)&B3s[wc + n*16 + fr][q*8];
        }
#pragma unroll
        for (int m = 0; m < 4; ++m)
#pragma unroll
            for (int n = 0; n < 4; ++n) {
                acc1[m][n] = __builtin_amdgcn_mfma_f32_16x16x32_bf16(a[m], b1[n], acc1[m][n], 0, 0, 0);
                acc3[m][n] = __builtin_amdgcn_mfma_f32_16x16x32_bf16(a[m], b3[n], acc3[m][n], 0, 0, 0);
            }
    }
    int q = lane >> 4, cfr = lane & 15;
#pragma unroll
    for (int m = 0; m < 4; ++m) {
#pragma unroll
        for (int rg = 0; rg < 4; ++rg) {
            int row = wr + m*16 + q*4 + rg;
            if (rt * BM + row < ne) {
                size_t gbase = (size_t)(row0 + row) * H_ + n0;
#pragma unroll
                for (int n = 0; n < 4; ++n) {
                    float h1 = acc1[m][n][rg];
                    float h3 = acc3[m][n][rg];
                    float g = h1 * h3 / (1.f + __expf(-h1));
                    G[gbase + wc + n*16 + cfr] = f2bf(g);
                }
            }
        }
    }
}

__global__ __launch_bounds__(256, 2) void gemm2_slow(
        const unsigned short* __restrict__ G, const float* __restrict__ W2,
        float* __restrict__ out, const int* __restrict__ counts,
        const int* __restrict__ offsets, const int* __restrict__ token_of,
        const float* __restrict__ slotw) {
    int ct = blockIdx.x;
    int rslot = blockIdx.y;
    int e = rslot >> 5, rt = rslot & 31;
    int ne = counts[e];
    if (rt * BM >= ne) return;
    int row0 = offsets[e] + rt * BM;
    int n0 = ct * BN;

    __shared__ unsigned short As[BM][LPAD];
    __shared__ unsigned short Bs[BN][LPAD];

    int tid = threadIdx.x;
    int lane = tid & 63, wid = tid >> 6;
    int wr = (wid >> 1) * 64, wc = (wid & 1) * 64;

    f32x4 acc[4][4];
#pragma unroll
    for (int m = 0; m < 4; ++m)
#pragma unroll
        for (int n = 0; n < 4; ++n) acc[m][n] = (f32x4){0.f,0.f,0.f,0.f};

    const float* Bp = W2 + (size_t)e * H_ * C_ + n0;
    int chunk = tid & 3, rr = tid >> 2;
    int kq = tid >> 5, n4 = tid & 31;

    for (int k0 = 0; k0 < H_; k0 += BK) {
        __syncthreads();
#pragma unroll
        for (int h = 0; h < 2; ++h) {
            int row = rr + h * 64;
            uint4 v = *(const uint4*)(G + (size_t)(row0 + row) * H_ + k0 + chunk * 8);
            *(uint4*)&As[row][chunk * 8] = v;
        }
        {
            float4 r0 = *(const float4*)(Bp + (size_t)(k0 + kq*4 + 0) * C_ + n4*4);
            float4 r1 = *(const float4*)(Bp + (size_t)(k0 + kq*4 + 1) * C_ + n4*4);
            float4 r2 = *(const float4*)(Bp + (size_t)(k0 + kq*4 + 2) * C_ + n4*4);
            float4 r3 = *(const float4*)(Bp + (size_t)(k0 + kq*4 + 3) * C_ + n4*4);
            ushort4 w0 = {f2bf(r0.x), f2bf(r1.x), f2bf(r2.x), f2bf(r3.x)};
            ushort4 w1 = {f2bf(r0.y), f2bf(r1.y), f2bf(r2.y), f2bf(r3.y)};
            ushort4 w2 = {f2bf(r0.z), f2bf(r1.z), f2bf(r2.z), f2bf(r3.z)};
            ushort4 w3 = {f2bf(r0.w), f2bf(r1.w), f2bf(r2.w), f2bf(r3.w)};
            *(ushort4*)&Bs[n4*4+0][kq*4] = w0;
            *(ushort4*)&Bs[n4*4+1][kq*4] = w1;
            *(ushort4*)&Bs[n4*4+2][kq*4] = w2;
            *(ushort4*)&Bs[n4*4+3][kq*4] = w3;
        }
        __syncthreads();
        int q = lane >> 4, fr = lane & 15;
        short8 a[4], b[4];
#pragma unroll
        for (int m = 0; m < 4; ++m) a[m] = *(const short8*)&As[wr + m*16 + fr][q*8];
#pragma unroll
        for (int n = 0; n < 4; ++n) b[n] = *(const short8*)&Bs[wc + n*16 + fr][q*8];
#pragma unroll
        for (int m = 0; m < 4; ++m)
#pragma unroll
            for (int n = 0; n < 4; ++n)
                acc[m][n] = __builtin_amdgcn_mfma_f32_16x16x32_bf16(a[m], b[n], acc[m][n], 0, 0, 0);
    }
    int q = lane >> 4, cfr = lane & 15;
#pragma unroll
    for (int m = 0; m < 4; ++m) {
#pragma unroll
        for (int rg = 0; rg < 4; ++rg) {
            int row = wr + m*16 + q*4 + rg;
            if (rt * BM + row < ne) {
                int grow = row0 + row;
                int tok = token_of[grow];
                float w = slotw[grow];
                float* orow = out + (size_t)tok * C_ + n0;
#pragma unroll
                for (int n = 0; n < 4; ++n)
                    atomicAdd(orow + wc + n*16 + cfr, acc[m][n][rg] * w);
            }
        }
    }
}

extern "C" void kernel_launch(void* const* d_in, const int* in_sizes, int n_in,
                              void* d_out, int out_size, void* d_ws, size_t ws_size,
                              hipStream_t stream) {
    const float* x  = (const float*)d_in[0];
    const float* Wg = (const float*)d_in[1];
    const float* W1 = (const float*)d_in[2];
    const float* W2 = (const float*)d_in[3];
    const float* W3 = (const float*)d_in[4];
    float* out = (float*)d_out;

    char* ws = (char*)d_ws;
    size_t o = 0;
    int*   sel      = (int*)(ws + o);  o += (size_t)NSLOT * 4;
    float* wts      = (float*)(ws + o); o += (size_t)NSLOT * 4;
    int*   pos      = (int*)(ws + o);  o += (size_t)NSLOT * 4;
    int*   token_of = (int*)(ws + o);  o += (size_t)NSLOT * 4;
    float* slotw    = (float*)(ws + o); o += (size_t)NSLOT * 4;
    int*   counts   = (int*)(ws + o);
    int*   offsets  = counts + E_;     o += 256;
    unsigned short* Xg = (unsigned short*)(ws + o); o += (size_t)SPAD * C_ * 2;
    unsigned short* G  = (unsigned short*)(ws + o); o += (size_t)SPAD * H_ * 2;
    size_t need_slow = o;
    unsigned short* W1t = (unsigned short*)(ws + o); o += (size_t)E_ * H_ * C_ * 2;
    unsigned short* W3t = (unsigned short*)(ws + o); o += (size_t)E_ * H_ * C_ * 2;
    unsigned short* W2t = W1t;   // W1t region freed after gemm1
    size_t need_fast = o;

    hipMemsetAsync(d_out, 0, (size_t)out_size * sizeof(float), stream);
    if (ws_size < need_slow) return;

    router_kernel<<<N_TOK/4, 256, 0, stream>>>(x, Wg, sel, wts);
    assign_kernel<<<1, 256, 0, stream>>>(sel, wts, counts, offsets, pos, token_of, slotw);
    copy_kernel<<<NSLOT/4, 256, 0, stream>>>(x, pos, Xg);

    if (ws_size >= need_fast) {
        hipFuncSetAttribute((const void*)gemm1_f8, hipFuncAttributeMaxDynamicSharedMemorySize, 131072);
        hipFuncSetAttribute((const void*)gemm2_f8, hipFuncAttributeMaxDynamicSharedMemorySize, 98304);
        wconv_kernel<<<dim3(H_/64, C_/64, E_), 256, 0, stream>>>(W1, W1t, C_, H_);
        wconv_kernel<<<dim3(H_/64, C_/64, E_), 256, 0, stream>>>(W3, W3t, C_, H_);
        gemm1_f8<<<dim3(H_/G1_BN, E_*32), 512, 131072, stream>>>(Xg, W1t, W3t, G, counts, offsets);
        wconv_kernel<<<dim3(C_/64, H_/64, E_), 256, 0, stream>>>(W2, W2t, H_, C_);
        gemm2_f8<<<dim3(C_/G2_BN, E_*32), 512, 98304, stream>>>(G, W2t, out, counts, offsets, token_of, slotw);
    } else {
        gemm1_slow<<<dim3(H_/BN, E_*32), 256, 0, stream>>>(Xg, W1, W3, G, counts, offsets);
        gemm2_slow<<<dim3(C_/BN, E_*32), 256, 0, stream>>>(G, W2, out, counts, offsets, token_of, slotw);
    }
}